// Round 7
// baseline (359.880 us; speedup 1.0000x reference)
//
#include <hip/hip_runtime.h>
#include <hip/hip_bf16.h>
#include <math.h>

typedef __attribute__((ext_vector_type(8))) short short8;
typedef __attribute__((ext_vector_type(4))) short short4v;
typedef __attribute__((ext_vector_type(4))) float f32x4;

__device__ __forceinline__ float bs2f(short s){
    union { unsigned u; float f; } x; x.u = ((unsigned)(unsigned short)s) << 16; return x.f;
}
__device__ __forceinline__ short f2bs(float f){
    union { float f; unsigned u; } x; x.f = f;
    unsigned r = x.u + 0x7fff + ((x.u >> 16) & 1);   // round-nearest-even
    return (short)(r >> 16);
}
__device__ __forceinline__ float blo(unsigned u){
    union { unsigned u; float f; } x; x.u = u << 16; return x.f;
}
__device__ __forceinline__ float bhi(unsigned u){
    union { unsigned u; float f; } x; x.u = u & 0xffff0000u; return x.f;
}
__device__ __forceinline__ unsigned pack2(float lo, float hi){
    union { float f; unsigned u; } a, b; a.f = lo; b.f = hi;
    unsigned rl = a.u + 0x7fff + ((a.u >> 16) & 1);
    unsigned rh = b.u + 0x7fff + ((b.u >> 16) & 1);
    return (rl >> 16) | (rh & 0xffff0000u);
}
__device__ __forceinline__ void gl2lds16(const void* g, void* l){
    __builtin_amdgcn_global_load_lds(
        (const __attribute__((address_space(1))) void*)g,
        (__attribute__((address_space(3))) void*)l, 16, 0, 0);
}

// Xpad[b][y][x][c]: y,x in [0,66), c in [0,512). Interior (y=h+1,x=w+1).
// c<256: flipped feature (= feature[b][c][h][63-w]); c>=256: proj.
#define XPB ((size_t)66*66*512)

// ---------------- prep: BN folding + weight transposes/casts ----------------
// grid 7169 x 256
__global__ void k_prep(const float* __restrict__ p1_w, const float* __restrict__ p1_b,
                       const float* __restrict__ bn1_g, const float* __restrict__ bn1_b,
                       const float* __restrict__ bn1_m, const float* __restrict__ bn1_v,
                       const float* __restrict__ off_w,
                       const float* __restrict__ dcn_w, const float* __restrict__ dcn_b,
                       const float* __restrict__ bn2_g, const float* __restrict__ bn2_b,
                       const float* __restrict__ bn2_m, const float* __restrict__ bn2_v,
                       short* __restrict__ p1_wb, short* __restrict__ Woffb,
                       short* __restrict__ Wbf,
                       float* __restrict__ bias1f, float* __restrict__ inv2f,
                       float* __restrict__ bias2f)
{
    int blk = blockIdx.x, t = threadIdx.x;
    if (blk == 0) {
        float inv1 = bn1_g[t] / sqrtf(bn1_v[t] + 1e-5f);
        bias1f[t] = p1_b[t] * inv1 + bn1_b[t] - bn1_m[t] * inv1;
        float inv2 = bn2_g[t] / sqrtf(bn2_v[t] + 1e-5f);
        inv2f[t] = inv2;
        bias2f[t] = dcn_b[t] * inv2 + bn2_b[t] - bn2_m[t] * inv2;
    } else if (blk <= 256) {
        int ci = blk - 1;
        float inv1 = bn1_g[t] / sqrtf(bn1_v[t] + 1e-5f);
        p1_wb[t*256 + ci] = f2bs(p1_w[t*256 + ci] * inv1);   // [o][ci], bn1 folded
    } else if (blk <= 2560) {
        int ck = blk - 257;                             // ck = c*9+tap (original order)
        int c = ck / 9, tap = ck % 9;
        Wbf[t*2304 + tap*256 + c] = f2bs(dcn_w[t*2304 + ck]);  // [o][tap*256+c]
    } else {
        int e = blk - 2561;                             // e = tap*512+ci (new K order)
        if (t < 32) {
            int tap = e >> 9, ci = e & 511;
            float v = off_w[((t < 27) ? t : 0)*4608 + ci*9 + tap];
            Woffb[t*4608 + e] = (t < 27) ? f2bs(v) : (short)0;  // [oc pad32][tap*512+ci]
        }
    }
}

// ---------------- halo zero: Xpad boundary cells (260/b) ----------------
// grid 2080 x 256; each thread zeroes one uint (2 bf16)
__global__ void k_halo(unsigned* __restrict__ Xpad)
{
    int blk = blockIdx.x, t = threadIdx.x;
    int b = blk / 260, i = blk % 260;
    int y, x;
    if (i < 66)       { y = 0;  x = i; }
    else if (i < 132) { y = 65; x = i - 66; }
    else { int j = i - 132; y = 1 + (j >> 1); x = (j & 1) * 65; }
    Xpad[((size_t)(b*66 + y)*66 + x)*256 + t] = 0u;
}

// ---------------- transpose+flip -> Xpad flip half (bf16, channels-last) -----
// grid 2048 x 256  (8 b * 64 h * 4 c-groups)
__global__ void k_featT(const float* __restrict__ feature, short* __restrict__ Xpad)
{
    __shared__ float tile[64][65];
    int bb = blockIdx.x;
    int cg = bb & 3, h = (bb >> 2) & 63, b = bb >> 8;
    int c0 = cg * 64;
    int t = threadIdx.x;
    int lw = t & 63, li = t >> 6;
    #pragma unroll
    for (int j = 0; j < 16; ++j) {
        int cl = j*4 + li;
        tile[cl][63 - lw] = feature[((b*256 + c0 + cl)*64 + h)*64 + lw];
    }
    __syncthreads();
    #pragma unroll
    for (int j = 0; j < 16; ++j) {
        int wl = j*4 + li;
        Xpad[((size_t)(b*66 + h+1)*66 + (wl+1))*512 + c0 + lw] = f2bs(tile[lw][wl]);
    }
}

// ---------------- proj via MFMA: M=256(o) N=32768(pos) K=256(ci) --------------
// grid 512 (2 m-tiles x 256 n-tiles) x 256; writes Xpad proj half
__global__ __launch_bounds__(256) void k_projm(
    short* Xpad, const short* __restrict__ p1_wb, const float* __restrict__ bias1f)
{
    __shared__ short Ash[128*32];
    __shared__ short Bsh[128*32];
    int bid = blockIdx.x;
    int mt = bid & 1, nt = bid >> 1;
    int m0 = mt*128, n0 = nt*128;
    int t = threadIdx.x;
    int lane = t & 63, w = t >> 6;
    int ln = lane & 15, q = lane >> 4;
    int wr = w & 1, wc = w >> 1;
    int ccol = (lane & 3)*8;

    const short* gA1 = p1_wb + (size_t)(m0 + w*16 + (lane>>2))*256 + ccol;
    const short* gA2 = gA1 + 64*256;
    int pos1 = n0 + w*16 + (lane>>2);
    int pos2 = pos1 + 64;
    int b1 = pos1 >> 12, hw1 = pos1 & 4095;
    int b2 = pos2 >> 12, hw2 = pos2 & 4095;
    const short* gB1 = Xpad + ((size_t)(b1*66 + (hw1>>6) + 1)*66 + (64 - (hw1 & 63)))*512 + ccol;
    const short* gB2 = Xpad + ((size_t)(b2*66 + (hw2>>6) + 1)*66 + (64 - (hw2 & 63)))*512 + ccol;
    short* lA = Ash + (w*16)*32;
    short* lB = Bsh + (w*16)*32;

    f32x4 acc[4][4] = {};
    for (int kt = 0; kt < 8; ++kt) {
        gl2lds16(gA1, lA);
        gl2lds16(gA2, lA + 64*32);
        gl2lds16(gB1, lB);
        gl2lds16(gB2, lB + 64*32);
        gA1 += 32; gA2 += 32; gB1 += 32; gB2 += 32;
        __syncthreads();
        short8 af[4], bfr[4];
        #pragma unroll
        for (int i = 0; i < 4; ++i)
            af[i] = *(const short8*)&Ash[(wr*64 + i*16 + ln)*32 + q*8];
        #pragma unroll
        for (int j = 0; j < 4; ++j)
            bfr[j] = *(const short8*)&Bsh[(wc*64 + j*16 + ln)*32 + q*8];
        #pragma unroll
        for (int i = 0; i < 4; ++i)
            #pragma unroll
            for (int j = 0; j < 4; ++j)
                acc[i][j] = __builtin_amdgcn_mfma_f32_16x16x32_bf16(af[i], bfr[j], acc[i][j], 0, 0, 0);
        __syncthreads();
    }
    // epilogue: row=o(q*4+r), col=pos(ln); store bf16 into Xpad[...][256+o]
    #pragma unroll
    for (int i = 0; i < 4; ++i) {
        int ob = m0 + wr*64 + i*16 + q*4;
        #pragma unroll
        for (int j = 0; j < 4; ++j) {
            int pos = n0 + wc*64 + j*16 + ln;
            int b = pos >> 12, hw = pos & 4095;
            size_t xb = ((size_t)(b*66 + (hw>>6) + 1)*66 + (hw & 63) + 1)*512 + 256 + ob;
            short4v st;
            st.x = f2bs(acc[i][j][0] + bias1f[ob]);
            st.y = f2bs(acc[i][j][1] + bias1f[ob+1]);
            st.z = f2bs(acc[i][j][2] + bias1f[ob+2]);
            st.w = f2bs(acc[i][j][3] + bias1f[ob+3]);
            *(short4v*)&Xpad[xb] = st;
        }
    }
}

// ---------------- offset conv via MFMA: M=32(27 oc) N=64(x) K=4608 ------------
// grid 512 ((b,h) rows) x 256; BK=64 per iteration (72 iters, 4 MFMA/wave each)
__global__ __launch_bounds__(256) void k_offm(
    const short* __restrict__ Xpad, const short* __restrict__ Woffb,
    const float* __restrict__ off_b, float* __restrict__ offv)
{
    __shared__ short Ash[32*64];   // [oc][64k] 4 KB
    __shared__ short Bsh[64*64];   // [x][64k]  8 KB
    int bid = blockIdx.x;
    int b = bid >> 6, h = bid & 63;
    int t = threadIdx.x;
    int lane = t & 63, w = t >> 6;
    int ln = lane & 15, q = lane >> 4;
    int wr = w & 1, wc = w >> 1;
    const short* xb = Xpad + (size_t)b*XPB;

    f32x4 acc[2] = {};
    for (int it = 0; it < 72; ++it) {
        int tap = it >> 3, c0 = (it & 7) << 6;   // 64-channel chunk within tap
        int dy = tap/3 - 1, dx = tap%3 - 1;
        #pragma unroll
        for (int i = 0; i < 2; ++i) {
            int row = w*16 + i*8 + (lane>>3);
            const short* gB = xb + ((size_t)(h + 1 + dy)*66 + (row + dx + 1))*512
                              + c0 + (lane&7)*8;
            gl2lds16(gB, Bsh + (w*16 + i*8)*64);
        }
        {
            int row = w*8 + (lane>>3);
            const short* gA = Woffb + (size_t)row*4608 + tap*512 + c0 + (lane&7)*8;
            gl2lds16(gA, Ash + (w*8)*64);
        }
        __syncthreads();
        #pragma unroll
        for (int kh = 0; kh < 2; ++kh) {
            short8 af = *(const short8*)&Ash[(wr*16 + ln)*64 + kh*32 + q*8];
            #pragma unroll
            for (int j = 0; j < 2; ++j) {
                short8 bfr = *(const short8*)&Bsh[((wc*2 + j)*16 + ln)*64 + kh*32 + q*8];
                acc[j] = __builtin_amdgcn_mfma_f32_16x16x32_bf16(af, bfr, acc[j], 0, 0, 0);
            }
        }
        __syncthreads();
    }
    #pragma unroll
    for (int j = 0; j < 2; ++j) {
        int x = (wc*2 + j)*16 + ln;
        #pragma unroll
        for (int r = 0; r < 4; ++r) {
            int oc = wr*16 + q*4 + r;
            if (oc < 27)
                offv[((b*27 + oc)*64 + h)*64 + x] = acc[j][r] + off_b[oc];
        }
    }
}

// ---------------- fused deform-sample + dcn GEMM + epilogue ------------------
// grid 512 ((b,h) rows = n-tile of 64 pos) x 512 threads (8 waves, M-strip 32).
// M=256(o), N=64(pos), K=2304 (72 chunks of 32, tap-major). B-tile is gathered
// from Xpad per chunk (no G buffer); A-tile staged via global_load_lds.
__global__ __launch_bounds__(512, 4) void k_dgemm(
    const short* __restrict__ Xpad,
    const float* __restrict__ offv,
    const short* __restrict__ Wbf,    // [256 o][2304 k], k = tap*256+c
    const float* __restrict__ inv2f, const float* __restrict__ bias2f,
    float* __restrict__ out)
{
    __shared__ short Ash[256*32];     // 16 KB [o][32k]
    __shared__ short Bsh[64*32];      //  4 KB [pos][32k]
    __shared__ int   c_off[576*4];    //  9 KB
    __shared__ float c_w[576*4];      //  9 KB
    int bid = blockIdx.x;
    int n0 = bid * 64;
    int b = n0 >> 12;
    int h = (n0 & 4095) >> 6;         // block-uniform row
    int t = threadIdx.x;
    int lane = t & 63, w = t >> 6;    // 8 waves
    int ln = lane & 15, q = lane >> 4;

    // corner phase: 64 pos x 9 taps
    for (int e = t; e < 576; e += 512) {
        int p = e / 9, k = e % 9;
        int base = (b*27)*4096 + h*64 + p;
        float dy = offv[base + k*4096];
        float dx = offv[base + (9+k)*4096];
        float ms = offv[base + (18+k)*4096];
        ms = 1.f / (1.f + expf(-ms));
        float py = (float)h + (float)(k/3 - 1) + dy;
        float px = (float)p + (float)(k%3 - 1) + dx;
        float y0f = floorf(py), x0f = floorf(px);
        float wy = py - y0f, wx = px - x0f;
        int y0 = (int)y0f, x0 = (int)x0f;
        int y1 = y0 + 1, x1 = x0 + 1;
        float vy0 = (y0 >= 0 && y0 < 64) ? 1.f : 0.f;
        float vy1 = (y1 >= 0 && y1 < 64) ? 1.f : 0.f;
        float vx0 = (x0 >= 0 && x0 < 64) ? 1.f : 0.f;
        float vx1 = (x1 >= 0 && x1 < 64) ? 1.f : 0.f;
        int y0c = min(max(y0,0),63), y1c = min(max(y1,0),63);
        int x0c = min(max(x0,0),63), x1c = min(max(x1,0),63);
        c_off[e*4+0] = ((y0c+1)*66 + x0c+1)*256;   // uint units
        c_off[e*4+1] = ((y0c+1)*66 + x1c+1)*256;
        c_off[e*4+2] = ((y1c+1)*66 + x0c+1)*256;
        c_off[e*4+3] = ((y1c+1)*66 + x1c+1)*256;
        c_w[e*4+0] = ms * (1.f-wy)*(1.f-wx) * vy0*vx0;
        c_w[e*4+1] = ms * (1.f-wy)*wx       * vy0*vx1;
        c_w[e*4+2] = ms * wy*(1.f-wx)       * vy1*vx0;
        c_w[e*4+3] = ms * wy*wx             * vy1*vx1;
    }
    __syncthreads();

    const unsigned* fT = (const unsigned*)Xpad + (size_t)b*(XPB/2);
    int gp = t >> 3, gq = t & 7;      // gather: pos 0..63, uint-pair 0..7

    f32x4 acc[2][4] = {};
    for (int kc = 0; kc < 72; ++kc) {
        int tap = kc >> 3;
        int c0u = (kc & 7) * 16;      // c-offset in uint units
        // stage A: wave w -> rows w*32..w*32+31 (3x16-row issues... 2 issues of 16)
        #pragma unroll
        for (int i = 0; i < 2; ++i) {
            int row = w*32 + i*16 + (lane>>2);
            gl2lds16(Wbf + (size_t)row*2304 + kc*32 + (lane&3)*8,
                     Ash + (w*32 + i*16)*32);
        }
        // gather B: each thread builds 2 uints (4 bf16) of row gp
        {
            const int4   co = *(const int4*)&c_off[(gp*9 + tap)*4];
            const float4 cw = *(const float4*)&c_w[(gp*9 + tap)*4];
            unsigned bv[2];
            #pragma unroll
            for (int j = 0; j < 2; ++j) {
                int c2 = c0u + gq*2 + j;
                unsigned u0 = fT[co.x + c2];
                unsigned u1 = fT[co.y + c2];
                unsigned u2 = fT[co.z + c2];
                unsigned u3 = fT[co.w + c2];
                float lo = cw.x*blo(u0) + cw.y*blo(u1) + cw.z*blo(u2) + cw.w*blo(u3);
                float hi = cw.x*bhi(u0) + cw.y*bhi(u1) + cw.z*bhi(u2) + cw.w*bhi(u3);
                bv[j] = pack2(lo, hi);
            }
            *(uint2*)((unsigned*)Bsh + gp*16 + gq*2) = make_uint2(bv[0], bv[1]);
        }
        __syncthreads();
        short8 af[2], bfr[4];
        #pragma unroll
        for (int i = 0; i < 2; ++i)
            af[i] = *(const short8*)&Ash[(w*32 + i*16 + ln)*32 + q*8];
        #pragma unroll
        for (int j = 0; j < 4; ++j)
            bfr[j] = *(const short8*)&Bsh[(j*16 + ln)*32 + q*8];
        #pragma unroll
        for (int i = 0; i < 2; ++i)
            #pragma unroll
            for (int j = 0; j < 4; ++j)
                acc[i][j] = __builtin_amdgcn_mfma_f32_16x16x32_bf16(af[i], bfr[j], acc[i][j], 0, 0, 0);
        __syncthreads();
    }

    // epilogue: o = w*32 + i*16 + q*4 + r ; pos = n0 + j*16 + ln
    #pragma unroll
    for (int i = 0; i < 2; ++i) {
        int ob = w*32 + i*16 + q*4;
        #pragma unroll
        for (int j = 0; j < 4; ++j) {
            int p = j*16 + ln;
            int hw = (n0 & 4095) + p;
            size_t xb = ((size_t)(b*66 + h + 1)*66 + p + 1)*512 + 256 + ob;
            short4v pr = *(const short4v*)&Xpad[xb];
            #pragma unroll
            for (int r = 0; r < 4; ++r) {
                int o = ob + r;
                size_t idx = ((size_t)(b*256 + o))*4096 + hw;
                float rs = bs2f(((const short*)&pr)[r]);
                float v = rs + acc[i][j][r]*inv2f[o] + bias2f[o];
                out[idx] = v < 0.f ? 0.f : v;   // NaN-propagating relu
            }
        }
    }
}

extern "C" void kernel_launch(void* const* d_in, const int* in_sizes, int n_in,
                              void* d_out, int out_size, void* d_ws, size_t ws_size,
                              hipStream_t stream)
{
    const float* feature = (const float*)d_in[0];
    const float* p1_w  = (const float*)d_in[1];
    const float* p1_b  = (const float*)d_in[2];
    const float* bn1_g = (const float*)d_in[3];
    const float* bn1_b = (const float*)d_in[4];
    const float* bn1_m = (const float*)d_in[5];
    const float* bn1_v = (const float*)d_in[6];
    const float* off_w = (const float*)d_in[7];
    const float* off_b = (const float*)d_in[8];
    const float* dcn_w = (const float*)d_in[9];
    const float* dcn_b = (const float*)d_in[10];
    const float* bn2_g = (const float*)d_in[11];
    const float* bn2_b = (const float*)d_in[12];
    const float* bn2_m = (const float*)d_in[13];
    const float* bn2_v = (const float*)d_in[14];

    // Workspace (float-slot offsets). Total 10,208,000 f = 40.8 MB (G dropped).
    float* ws = (float*)d_ws;
    short* Xpad   = (short*)ws;                 // 17,842,176 sh = 8,921,088 f
    float* offbuf = ws + 8921088;               //    884,736 f
    short* p1_wb  = (short*)(ws + 9805824);     //     65,536 sh = 32,768 f
    short* Woffb  = (short*)(ws + 9838592);     //    147,456 sh = 73,728 f
    short* Wbf    = (short*)(ws + 9912320);     //    589,824 sh = 294,912 f
    float* bias1f = ws + 10207232;              //        256
    float* inv2f  = ws + 10207488;              //        256
    float* bias2f = ws + 10207744;              //        256

    k_prep<<<7169, 256, 0, stream>>>(p1_w, p1_b, bn1_g, bn1_b, bn1_m, bn1_v,
                                     off_w, dcn_w, dcn_b, bn2_g, bn2_b, bn2_m, bn2_v,
                                     p1_wb, Woffb, Wbf, bias1f, inv2f, bias2f);
    k_halo<<<2080, 256, 0, stream>>>((unsigned*)Xpad);
    k_featT<<<2048, 256, 0, stream>>>(feature, Xpad);
    k_projm<<<512, 256, 0, stream>>>(Xpad, p1_wb, bias1f);
    k_offm<<<512, 256, 0, stream>>>(Xpad, Woffb, off_b, offbuf);
    k_dgemm<<<512, 512, 0, stream>>>(Xpad, offbuf, Wbf, inv2f, bias2f, (float*)d_out);
}

// Round 8
// 296.497 us; speedup vs baseline: 1.2138x; 1.2138x over previous
//
#include <hip/hip_runtime.h>
#include <hip/hip_bf16.h>
#include <math.h>

typedef __attribute__((ext_vector_type(8))) short short8;
typedef __attribute__((ext_vector_type(4))) short short4v;
typedef __attribute__((ext_vector_type(4))) float f32x4;

__device__ __forceinline__ float bs2f(short s){
    union { unsigned u; float f; } x; x.u = ((unsigned)(unsigned short)s) << 16; return x.f;
}
__device__ __forceinline__ short f2bs(float f){
    union { float f; unsigned u; } x; x.f = f;
    unsigned r = x.u + 0x7fff + ((x.u >> 16) & 1);   // round-nearest-even
    return (short)(r >> 16);
}
__device__ __forceinline__ float blo(unsigned u){
    union { unsigned u; float f; } x; x.u = u << 16; return x.f;
}
__device__ __forceinline__ float bhi(unsigned u){
    union { unsigned u; float f; } x; x.u = u & 0xffff0000u; return x.f;
}
__device__ __forceinline__ unsigned pack2(float lo, float hi){
    union { float f; unsigned u; } a, b; a.f = lo; b.f = hi;
    unsigned rl = a.u + 0x7fff + ((a.u >> 16) & 1);
    unsigned rh = b.u + 0x7fff + ((b.u >> 16) & 1);
    return (rl >> 16) | (rh & 0xffff0000u);
}
__device__ __forceinline__ void gl2lds16(const void* g, void* l){
    __builtin_amdgcn_global_load_lds(
        (const __attribute__((address_space(1))) void*)g,
        (__attribute__((address_space(3))) void*)l, 16, 0, 0);
}

// Xpad[b][y][x][c]: y,x in [0,66), c in [0,512). Interior (y=h+1,x=w+1).
// c<256: flipped feature (= feature[b][c][h][63-w]); c>=256: proj.
#define XPB ((size_t)66*66*512)

// ---------------- prep: BN folding + weight transposes/casts ----------------
// grid 7169 x 256
__global__ void k_prep(const float* __restrict__ p1_w, const float* __restrict__ p1_b,
                       const float* __restrict__ bn1_g, const float* __restrict__ bn1_b,
                       const float* __restrict__ bn1_m, const float* __restrict__ bn1_v,
                       const float* __restrict__ off_w,
                       const float* __restrict__ dcn_w, const float* __restrict__ dcn_b,
                       const float* __restrict__ bn2_g, const float* __restrict__ bn2_b,
                       const float* __restrict__ bn2_m, const float* __restrict__ bn2_v,
                       short* __restrict__ p1_wb, short* __restrict__ Woffb,
                       short* __restrict__ Wbf,
                       float* __restrict__ bias1f, float* __restrict__ inv2f,
                       float* __restrict__ bias2f)
{
    int blk = blockIdx.x, t = threadIdx.x;
    if (blk == 0) {
        float inv1 = bn1_g[t] / sqrtf(bn1_v[t] + 1e-5f);
        bias1f[t] = p1_b[t] * inv1 + bn1_b[t] - bn1_m[t] * inv1;
        float inv2 = bn2_g[t] / sqrtf(bn2_v[t] + 1e-5f);
        inv2f[t] = inv2;
        bias2f[t] = dcn_b[t] * inv2 + bn2_b[t] - bn2_m[t] * inv2;
    } else if (blk <= 256) {
        int ci = blk - 1;
        float inv1 = bn1_g[t] / sqrtf(bn1_v[t] + 1e-5f);
        p1_wb[t*256 + ci] = f2bs(p1_w[t*256 + ci] * inv1);   // [o][ci], bn1 folded
    } else if (blk <= 2560) {
        int ck = blk - 257;                             // ck = c*9+tap (original order)
        int c = ck / 9, tap = ck % 9;
        Wbf[t*2304 + tap*256 + c] = f2bs(dcn_w[t*2304 + ck]);  // [o][tap*256+c]
    } else {
        int e = blk - 2561;                             // e = tap*512+ci (new K order)
        if (t < 32) {
            int tap = e >> 9, ci = e & 511;
            float v = off_w[((t < 27) ? t : 0)*4608 + ci*9 + tap];
            Woffb[t*4608 + e] = (t < 27) ? f2bs(v) : (short)0;  // [oc pad32][tap*512+ci]
        }
    }
}

// ---------------- halo zero: Xpad boundary cells (260/b) ----------------
// grid 2080 x 256; each thread zeroes one uint (2 bf16)
__global__ void k_halo(unsigned* __restrict__ Xpad)
{
    int blk = blockIdx.x, t = threadIdx.x;
    int b = blk / 260, i = blk % 260;
    int y, x;
    if (i < 66)       { y = 0;  x = i; }
    else if (i < 132) { y = 65; x = i - 66; }
    else { int j = i - 132; y = 1 + (j >> 1); x = (j & 1) * 65; }
    Xpad[((size_t)(b*66 + y)*66 + x)*256 + t] = 0u;
}

// ---------------- transpose+flip -> Xpad flip half (bf16, channels-last) -----
// grid 2048 x 256  (8 b * 64 h * 4 c-groups)
__global__ void k_featT(const float* __restrict__ feature, short* __restrict__ Xpad)
{
    __shared__ float tile[64][65];
    int bb = blockIdx.x;
    int cg = bb & 3, h = (bb >> 2) & 63, b = bb >> 8;
    int c0 = cg * 64;
    int t = threadIdx.x;
    int lw = t & 63, li = t >> 6;
    #pragma unroll
    for (int j = 0; j < 16; ++j) {
        int cl = j*4 + li;
        tile[cl][63 - lw] = feature[((b*256 + c0 + cl)*64 + h)*64 + lw];
    }
    __syncthreads();
    #pragma unroll
    for (int j = 0; j < 16; ++j) {
        int wl = j*4 + li;
        Xpad[((size_t)(b*66 + h+1)*66 + (wl+1))*512 + c0 + lw] = f2bs(tile[lw][wl]);
    }
}

// ---------------- proj via MFMA: M=256(o) N=64(pos=one (b,h) row) K=256 -------
// grid 512 x 512 thr (8 waves, m-strip 32/wave); writes Xpad proj half
__global__ __launch_bounds__(512, 4) void k_projm(
    short* Xpad, const short* __restrict__ p1_wb, const float* __restrict__ bias1f)
{
    __shared__ short Ash[256*32];   // 16 KB [o][32k]
    __shared__ short Bsh[64*32];    //  4 KB [x][32k]
    int bid = blockIdx.x;
    int b = bid >> 6, h = bid & 63;
    int t = threadIdx.x;
    int lane = t & 63, w = t >> 6;
    int ln = lane & 15, q = lane >> 4;
    size_t rowbase = (size_t)(b*66 + h + 1)*66;

    f32x4 acc[2][4] = {};
    for (int kt = 0; kt < 8; ++kt) {
        int kcol = kt*32 + (lane&3)*8;
        #pragma unroll
        for (int i = 0; i < 2; ++i) {
            int row = w*32 + i*16 + (lane>>2);
            gl2lds16(p1_wb + (size_t)row*256 + kcol, Ash + (w*32 + i*16)*32);
        }
        if (w < 4) {
            int x = w*16 + (lane>>2);                 // output w-coord
            gl2lds16(Xpad + (rowbase + (64 - x))*512 + kcol, Bsh + (w*16)*32);
        }
        __syncthreads();
        short8 af[2], bfr[4];
        #pragma unroll
        for (int i = 0; i < 2; ++i)
            af[i] = *(const short8*)&Ash[(w*32 + i*16 + ln)*32 + q*8];
        #pragma unroll
        for (int j = 0; j < 4; ++j)
            bfr[j] = *(const short8*)&Bsh[(j*16 + ln)*32 + q*8];
        #pragma unroll
        for (int i = 0; i < 2; ++i)
            #pragma unroll
            for (int j = 0; j < 4; ++j)
                acc[i][j] = __builtin_amdgcn_mfma_f32_16x16x32_bf16(af[i], bfr[j], acc[i][j], 0, 0, 0);
        __syncthreads();
    }
    #pragma unroll
    for (int i = 0; i < 2; ++i) {
        int ob = w*32 + i*16 + q*4;
        #pragma unroll
        for (int j = 0; j < 4; ++j) {
            int x = j*16 + ln;
            size_t xb = (rowbase + x + 1)*512 + 256 + ob;
            short4v st;
            st.x = f2bs(acc[i][j][0] + bias1f[ob]);
            st.y = f2bs(acc[i][j][1] + bias1f[ob+1]);
            st.z = f2bs(acc[i][j][2] + bias1f[ob+2]);
            st.w = f2bs(acc[i][j][3] + bias1f[ob+3]);
            *(short4v*)&Xpad[xb] = st;
        }
    }
}

// ---------------- offset conv via MFMA: M=32(27 oc) N=64(x) K=4608 ------------
// grid 512 ((b,h) rows) x 512 thr (8 waves: 2 m x 4 n); BK=64 (72 iters)
__global__ __launch_bounds__(512, 4) void k_offm(
    const short* __restrict__ Xpad, const short* __restrict__ Woffb,
    const float* __restrict__ off_b, float* __restrict__ offv)
{
    __shared__ short Ash[32*64];   // 4 KB [oc][64k]
    __shared__ short Bsh[64*64];   // 8 KB [x][64k]
    int bid = blockIdx.x;
    int b = bid >> 6, h = bid & 63;
    int t = threadIdx.x;
    int lane = t & 63, w = t >> 6;
    int ln = lane & 15, q = lane >> 4;
    int wr = w >> 2, wc = w & 3;
    const short* xb = Xpad + (size_t)b*XPB;

    f32x4 acc = {};
    for (int it = 0; it < 72; ++it) {
        int tap = it >> 3, c0 = (it & 7) << 6;   // 64-channel chunk within tap
        int dy = tap/3 - 1, dx = tap%3 - 1;
        {
            int row = w*8 + (lane>>3);            // x-pos 0..63
            const short* gB = xb + ((size_t)(h + 1 + dy)*66 + (row + dx + 1))*512
                              + c0 + (lane&7)*8;
            gl2lds16(gB, Bsh + (w*8)*64);
        }
        if (w < 4) {
            int row = w*8 + (lane>>3);            // oc 0..31
            const short* gA = Woffb + (size_t)row*4608 + tap*512 + c0 + (lane&7)*8;
            gl2lds16(gA, Ash + (w*8)*64);
        }
        __syncthreads();
        #pragma unroll
        for (int kh = 0; kh < 2; ++kh) {
            short8 af  = *(const short8*)&Ash[(wr*16 + ln)*64 + kh*32 + q*8];
            short8 bfr = *(const short8*)&Bsh[(wc*16 + ln)*64 + kh*32 + q*8];
            acc = __builtin_amdgcn_mfma_f32_16x16x32_bf16(af, bfr, acc, 0, 0, 0);
        }
        __syncthreads();
    }
    int x = wc*16 + ln;
    #pragma unroll
    for (int r = 0; r < 4; ++r) {
        int oc = wr*16 + q*4 + r;
        if (oc < 27)
            offv[((b*27 + oc)*64 + h)*64 + x] = acc[r] + off_b[oc];
    }
}

// ---------------- sample: masked bilinear im2col -> G[pos][tap*256+c] bf16 ----
// grid 2048 x 256 (b x h x 4 p-groups); uint2 (4-channel) vectorized gathers
__global__ void k_sample(const short* __restrict__ Xpad,
                         const float* __restrict__ offv,
                         uint2* __restrict__ G)        // G as uint2 (4 bf16)
{
    __shared__ int   c_off[144*4];
    __shared__ float c_w[144*4];
    int bb = blockIdx.x;
    int pg = bb & 3, h = (bb >> 2) & 63, b = bb >> 8;
    int p0 = pg * 16;
    int t = threadIdx.x;

    if (t < 144) {
        int p = p0 + t / 9, k = t % 9;
        int base = (b*27)*4096 + h*64 + p;
        float dy = offv[base + k*4096];
        float dx = offv[base + (9+k)*4096];
        float ms = offv[base + (18+k)*4096];
        ms = 1.f / (1.f + expf(-ms));
        float py = (float)h + (float)(k/3 - 1) + dy;
        float px = (float)p + (float)(k%3 - 1) + dx;
        float y0f = floorf(py), x0f = floorf(px);
        float wy = py - y0f, wx = px - x0f;
        int y0 = (int)y0f, x0 = (int)x0f;
        int y1 = y0 + 1, x1 = x0 + 1;
        float vy0 = (y0 >= 0 && y0 < 64) ? 1.f : 0.f;
        float vy1 = (y1 >= 0 && y1 < 64) ? 1.f : 0.f;
        float vx0 = (x0 >= 0 && x0 < 64) ? 1.f : 0.f;
        float vx1 = (x1 >= 0 && x1 < 64) ? 1.f : 0.f;
        int y0c = min(max(y0,0),63), y1c = min(max(y1,0),63);
        int x0c = min(max(x0,0),63), x1c = min(max(x1,0),63);
        // offsets in uint2 units (4-ch groups): cell*512/4 = cell*128
        c_off[t*4+0] = ((y0c+1)*66 + x0c+1)*128;
        c_off[t*4+1] = ((y0c+1)*66 + x1c+1)*128;
        c_off[t*4+2] = ((y1c+1)*66 + x0c+1)*128;
        c_off[t*4+3] = ((y1c+1)*66 + x1c+1)*128;
        c_w[t*4+0] = ms * (1.f-wy)*(1.f-wx) * vy0*vx0;
        c_w[t*4+1] = ms * (1.f-wy)*wx       * vy0*vx1;
        c_w[t*4+2] = ms * wy*(1.f-wx)       * vy1*vx0;
        c_w[t*4+3] = ms * wy*wx             * vy1*vx1;
    }
    __syncthreads();

    int tc = t & 63, tg = t >> 6;                  // tc: uint2 lane (64 = 256 ch/tap)
    const uint2* fT = (const uint2*)Xpad + (size_t)b*(XPB/4);
    size_t rb = ((size_t)b*4096 + h*64 + p0);
    #pragma unroll
    for (int pi = 0; pi < 4; ++pi) {
        int pl = tg*4 + pi;                        // wave-uniform local p
        size_t grow = (rb + pl)*576;               // G row in uint2 units (2304/4)
        #pragma unroll
        for (int k = 0; k < 9; ++k) {
            int e = pl*9 + k;
            const int4   co = *(const int4*)&c_off[e*4];
            const float4 cw = *(const float4*)&c_w[e*4];
            uint2 u0 = fT[co.x + tc];
            uint2 u1 = fT[co.y + tc];
            uint2 u2 = fT[co.z + tc];
            uint2 u3 = fT[co.w + tc];
            float g0 = cw.x*blo(u0.x) + cw.y*blo(u1.x) + cw.z*blo(u2.x) + cw.w*blo(u3.x);
            float g1 = cw.x*bhi(u0.x) + cw.y*bhi(u1.x) + cw.z*bhi(u2.x) + cw.w*bhi(u3.x);
            float g2 = cw.x*blo(u0.y) + cw.y*blo(u1.y) + cw.z*blo(u2.y) + cw.w*blo(u3.y);
            float g3 = cw.x*bhi(u0.y) + cw.y*bhi(u1.y) + cw.z*bhi(u2.y) + cw.w*bhi(u3.y);
            G[grow + k*64 + tc] = make_uint2(pack2(g0, g1), pack2(g2, g3));
        }
    }
}

// ---------------- dcn GEMM via bf16 MFMA: M=256(o) N=64(pos) K=2304 ----------
// grid 512 (one (b,h) row each) x 512 thr (8 waves, m-strip 32); 72 K-chunks
__global__ __launch_bounds__(512, 4) void k_gemm(
    const short* __restrict__ G,      // [32768][2304] bf16
    const short* __restrict__ Wbf,    // [256][2304] bf16
    const short* __restrict__ Xpad,   // residual: proj half
    const float* __restrict__ inv2f, const float* __restrict__ bias2f,
    float* __restrict__ out)
{
    __shared__ short Ash[256*32];   // 16 KB [o][32k]
    __shared__ short Bsh[64*32];    //  4 KB [pos][32k]
    int bid = blockIdx.x;
    int n0 = bid * 64;
    int b = n0 >> 12, hw0 = n0 & 4095;
    int t = threadIdx.x;
    int lane = t & 63, w = t >> 6;
    int ln = lane & 15, q = lane >> 4;

    f32x4 acc[2][4] = {};
    for (int kc = 0; kc < 72; ++kc) {
        int kcol = kc*32 + (lane&3)*8;
        #pragma unroll
        for (int i = 0; i < 2; ++i) {
            int row = w*32 + i*16 + (lane>>2);
            gl2lds16(Wbf + (size_t)row*2304 + kcol, Ash + (w*32 + i*16)*32);
        }
        if (w < 4) {
            int row = w*16 + (lane>>2);
            gl2lds16(G + (size_t)(n0 + row)*2304 + kcol, Bsh + (w*16)*32);
        }
        __syncthreads();
        short8 af[2], bfr[4];
        #pragma unroll
        for (int i = 0; i < 2; ++i)
            af[i] = *(const short8*)&Ash[(w*32 + i*16 + ln)*32 + q*8];
        #pragma unroll
        for (int j = 0; j < 4; ++j)
            bfr[j] = *(const short8*)&Bsh[(j*16 + ln)*32 + q*8];
        #pragma unroll
        for (int i = 0; i < 2; ++i)
            #pragma unroll
            for (int j = 0; j < 4; ++j)
                acc[i][j] = __builtin_amdgcn_mfma_f32_16x16x32_bf16(af[i], bfr[j], acc[i][j], 0, 0, 0);
        __syncthreads();
    }

    // epilogue: bn2 + residual(from Xpad proj half) + relu
    int h = hw0 >> 6;
    #pragma unroll
    for (int i = 0; i < 2; ++i) {
        int ob = w*32 + i*16 + q*4;
        #pragma unroll
        for (int j = 0; j < 4; ++j) {
            int p = j*16 + ln;
            size_t xb = ((size_t)(b*66 + h + 1)*66 + p + 1)*512 + 256 + ob;
            short4v pr = *(const short4v*)&Xpad[xb];
            #pragma unroll
            for (int r = 0; r < 4; ++r) {
                int o = ob + r;
                size_t idx = ((size_t)(b*256 + o))*4096 + hw0 + p;
                float rs = bs2f(((const short*)&pr)[r]);
                float v = rs + acc[i][j][r]*inv2f[o] + bias2f[o];
                out[idx] = v < 0.f ? 0.f : v;   // NaN-propagating relu
            }
        }
    }
}

extern "C" void kernel_launch(void* const* d_in, const int* in_sizes, int n_in,
                              void* d_out, int out_size, void* d_ws, size_t ws_size,
                              hipStream_t stream)
{
    const float* feature = (const float*)d_in[0];
    const float* p1_w  = (const float*)d_in[1];
    const float* p1_b  = (const float*)d_in[2];
    const float* bn1_g = (const float*)d_in[3];
    const float* bn1_b = (const float*)d_in[4];
    const float* bn1_m = (const float*)d_in[5];
    const float* bn1_v = (const float*)d_in[6];
    const float* off_w = (const float*)d_in[7];
    const float* off_b = (const float*)d_in[8];
    const float* dcn_w = (const float*)d_in[9];
    const float* dcn_b = (const float*)d_in[10];
    const float* bn2_g = (const float*)d_in[11];
    const float* bn2_b = (const float*)d_in[12];
    const float* bn2_m = (const float*)d_in[13];
    const float* bn2_v = (const float*)d_in[14];

    // Workspace (float-slot offsets). Total 47,956,736 f = 191.8 MB (proven).
    float* ws = (float*)d_ws;
    short* Xpad   = (short*)ws;                 // 17,842,176 sh = 8,921,088 f
    float* offbuf = ws + 8921088;               //    884,736 f
    short* p1_wb  = (short*)(ws + 9805824);     //     65,536 sh = 32,768 f
    short* Woffb  = (short*)(ws + 9838592);     //    147,456 sh = 73,728 f
    short* Wbf    = (short*)(ws + 9912320);     //    589,824 sh = 294,912 f
    float* bias1f = ws + 10207232;              //        256
    float* inv2f  = ws + 10207488;              //        256
    float* bias2f = ws + 10207744;              //        256
    short* G      = (short*)(ws + 10208000);    // 75,497,472 sh = 37,748,736 f

    k_prep<<<7169, 256, 0, stream>>>(p1_w, p1_b, bn1_g, bn1_b, bn1_m, bn1_v,
                                     off_w, dcn_w, dcn_b, bn2_g, bn2_b, bn2_m, bn2_v,
                                     p1_wb, Woffb, Wbf, bias1f, inv2f, bias2f);
    k_halo<<<2080, 256, 0, stream>>>((unsigned*)Xpad);
    k_featT<<<2048, 256, 0, stream>>>(feature, Xpad);
    k_projm<<<512, 512, 0, stream>>>(Xpad, p1_wb, bias1f);
    k_offm<<<512, 512, 0, stream>>>(Xpad, Woffb, off_b, offbuf);
    k_sample<<<2048, 256, 0, stream>>>(Xpad, offbuf, (uint2*)G);
    k_gemm<<<512, 512, 0, stream>>>(G, Wbf, Xpad, inv2f, bias2f, (float*)d_out);
}

// Round 9
// 273.166 us; speedup vs baseline: 1.3174x; 1.0854x over previous
//
#include <hip/hip_runtime.h>
#include <hip/hip_bf16.h>
#include <math.h>

typedef __attribute__((ext_vector_type(8))) short short8;
typedef __attribute__((ext_vector_type(4))) short short4v;
typedef __attribute__((ext_vector_type(4))) float f32x4;

__device__ __forceinline__ float bs2f(short s){
    union { unsigned u; float f; } x; x.u = ((unsigned)(unsigned short)s) << 16; return x.f;
}
__device__ __forceinline__ short f2bs(float f){
    union { float f; unsigned u; } x; x.f = f;
    unsigned r = x.u + 0x7fff + ((x.u >> 16) & 1);   // round-nearest-even
    return (short)(r >> 16);
}
__device__ __forceinline__ float blo(unsigned u){
    union { unsigned u; float f; } x; x.u = u << 16; return x.f;
}
__device__ __forceinline__ float bhi(unsigned u){
    union { unsigned u; float f; } x; x.u = u & 0xffff0000u; return x.f;
}
__device__ __forceinline__ unsigned pack2(float lo, float hi){
    union { float f; unsigned u; } a, b; a.f = lo; b.f = hi;
    unsigned rl = a.u + 0x7fff + ((a.u >> 16) & 1);
    unsigned rh = b.u + 0x7fff + ((b.u >> 16) & 1);
    return (rl >> 16) | (rh & 0xffff0000u);
}
__device__ __forceinline__ void gl2lds16(const void* g, void* l){
    __builtin_amdgcn_global_load_lds(
        (const __attribute__((address_space(1))) void*)g,
        (__attribute__((address_space(3))) void*)l, 16, 0, 0);
}

// Xpad[b][y][x][c]: y,x in [0,66), c in [0,512). Interior (y=h+1,x=w+1).
// c<256: flipped feature (= feature[b][c][h][63-w]); c>=256: proj.
#define XPB ((size_t)66*66*512)

// ---------------- prep: BN folding + weight transposes + Xpad halo zero ------
// grid 9249 x 256
__global__ void k_prep(const float* __restrict__ p1_w, const float* __restrict__ p1_b,
                       const float* __restrict__ bn1_g, const float* __restrict__ bn1_b,
                       const float* __restrict__ bn1_m, const float* __restrict__ bn1_v,
                       const float* __restrict__ off_w,
                       const float* __restrict__ dcn_w, const float* __restrict__ dcn_b,
                       const float* __restrict__ bn2_g, const float* __restrict__ bn2_b,
                       const float* __restrict__ bn2_m, const float* __restrict__ bn2_v,
                       short* __restrict__ p1_wb, short* __restrict__ Woffb,
                       short* __restrict__ Wbf,
                       float* __restrict__ bias1f, float* __restrict__ inv2f,
                       float* __restrict__ bias2f, unsigned* __restrict__ XpadU)
{
    int blk = blockIdx.x, t = threadIdx.x;
    if (blk == 0) {
        float inv1 = bn1_g[t] / sqrtf(bn1_v[t] + 1e-5f);
        bias1f[t] = p1_b[t] * inv1 + bn1_b[t] - bn1_m[t] * inv1;
        float inv2 = bn2_g[t] / sqrtf(bn2_v[t] + 1e-5f);
        inv2f[t] = inv2;
        bias2f[t] = dcn_b[t] * inv2 + bn2_b[t] - bn2_m[t] * inv2;
    } else if (blk <= 256) {
        int ci = blk - 1;
        float inv1 = bn1_g[t] / sqrtf(bn1_v[t] + 1e-5f);
        p1_wb[t*256 + ci] = f2bs(p1_w[t*256 + ci] * inv1);   // [o][ci], bn1 folded
    } else if (blk <= 2560) {
        int ck = blk - 257;                             // ck = c*9+tap (original order)
        int c = ck / 9, tap = ck % 9;
        Wbf[t*2304 + tap*256 + c] = f2bs(dcn_w[t*2304 + ck]);  // [o][tap*256+c]
    } else if (blk <= 7168) {
        int e = blk - 2561;                             // e = tap*512+ci (new K order)
        if (t < 32) {
            int tap = e >> 9, ci = e & 511;
            float v = off_w[((t < 27) ? t : 0)*4608 + ci*9 + tap];
            Woffb[t*4608 + e] = (t < 27) ? f2bs(v) : (short)0;  // [oc pad32][tap*512+ci]
        }
    } else {
        int hb = blk - 7169;                            // halo zero, 260 cells/b
        int b = hb / 260, i = hb % 260;
        int y, x;
        if (i < 66)       { y = 0;  x = i; }
        else if (i < 132) { y = 65; x = i - 66; }
        else { int j = i - 132; y = 1 + (j >> 1); x = (j & 1) * 65; }
        XpadU[((size_t)(b*66 + y)*66 + x)*256 + t] = 0u;
    }
}

// ---------------- transpose+flip -> Xpad flip half (bf16, channels-last) -----
// grid 2048 x 256  (8 b * 64 h * 4 c-groups)
__global__ void k_featT(const float* __restrict__ feature, short* __restrict__ Xpad)
{
    __shared__ float tile[64][65];
    int bb = blockIdx.x;
    int cg = bb & 3, h = (bb >> 2) & 63, b = bb >> 8;
    int c0 = cg * 64;
    int t = threadIdx.x;
    int lw = t & 63, li = t >> 6;
    #pragma unroll
    for (int j = 0; j < 16; ++j) {
        int cl = j*4 + li;
        tile[cl][63 - lw] = feature[((b*256 + c0 + cl)*64 + h)*64 + lw];
    }
    __syncthreads();
    #pragma unroll
    for (int j = 0; j < 16; ++j) {
        int wl = j*4 + li;
        Xpad[((size_t)(b*66 + h+1)*66 + (wl+1))*512 + c0 + lw] = f2bs(tile[lw][wl]);
    }
}

// ---------------- proj via MFMA: M=256(o) N=64(pos=one (b,h) row) K=256 -------
// grid 512 x 512 thr (8 waves, m-strip 32/wave); writes Xpad proj half
__global__ __launch_bounds__(512, 4) void k_projm(
    short* Xpad, const short* __restrict__ p1_wb, const float* __restrict__ bias1f)
{
    __shared__ short Ash[256*32];   // 16 KB [o][32k]
    __shared__ short Bsh[64*32];    //  4 KB [x][32k]
    int bid = blockIdx.x;
    int b = bid >> 6, h = bid & 63;
    int t = threadIdx.x;
    int lane = t & 63, w = t >> 6;
    int ln = lane & 15, q = lane >> 4;
    size_t rowbase = (size_t)(b*66 + h + 1)*66;

    f32x4 acc[2][4] = {};
    for (int kt = 0; kt < 8; ++kt) {
        int kcol = kt*32 + (lane&3)*8;
        #pragma unroll
        for (int i = 0; i < 2; ++i) {
            int row = w*32 + i*16 + (lane>>2);
            gl2lds16(p1_wb + (size_t)row*256 + kcol, Ash + (w*32 + i*16)*32);
        }
        if (w < 4) {
            int x = w*16 + (lane>>2);                 // output w-coord
            gl2lds16(Xpad + (rowbase + (64 - x))*512 + kcol, Bsh + (w*16)*32);
        }
        __syncthreads();
        short8 af[2], bfr[4];
        #pragma unroll
        for (int i = 0; i < 2; ++i)
            af[i] = *(const short8*)&Ash[(w*32 + i*16 + ln)*32 + q*8];
        #pragma unroll
        for (int j = 0; j < 4; ++j)
            bfr[j] = *(const short8*)&Bsh[(j*16 + ln)*32 + q*8];
        #pragma unroll
        for (int i = 0; i < 2; ++i)
            #pragma unroll
            for (int j = 0; j < 4; ++j)
                acc[i][j] = __builtin_amdgcn_mfma_f32_16x16x32_bf16(af[i], bfr[j], acc[i][j], 0, 0, 0);
        __syncthreads();
    }
    #pragma unroll
    for (int i = 0; i < 2; ++i) {
        int ob = w*32 + i*16 + q*4;
        #pragma unroll
        for (int j = 0; j < 4; ++j) {
            int x = j*16 + ln;
            size_t xb = (rowbase + x + 1)*512 + 256 + ob;
            short4v st;
            st.x = f2bs(acc[i][j][0] + bias1f[ob]);
            st.y = f2bs(acc[i][j][1] + bias1f[ob+1]);
            st.z = f2bs(acc[i][j][2] + bias1f[ob+2]);
            st.w = f2bs(acc[i][j][3] + bias1f[ob+3]);
            *(short4v*)&Xpad[xb] = st;
        }
    }
}

// ---------------- offset conv via MFMA: M=32(27 oc) N=64(x) K=4608 ------------
// grid 512 ((b,h) rows) x 512 thr (8 waves: 2m x 4n); BK=128 as 4 stride-32
// sub-chunks per barrier window (36 iters, 4 MFMA/wave/window)
__global__ __launch_bounds__(512, 4) void k_offm(
    const short* __restrict__ Xpad, const short* __restrict__ Woffb,
    const float* __restrict__ off_b, float* __restrict__ offv)
{
    __shared__ short Ash[4][32*32];   //  8 KB [oc][32k] x4
    __shared__ short Bsh[4][64*32];   // 16 KB [x][32k] x4
    int bid = blockIdx.x;
    int b = bid >> 6, h = bid & 63;
    int t = threadIdx.x;
    int lane = t & 63, w = t >> 6;
    int ln = lane & 15, q = lane >> 4;
    int wr = w >> 2, wc = w & 3;
    const short* xb = Xpad + (size_t)b*XPB;

    f32x4 acc = {};
    for (int it = 0; it < 36; ++it) {
        int tap = it >> 2, c0 = (it & 3) << 7;    // 128-ch chunk within tap
        int dy = tap/3 - 1, dx = tap%3 - 1;
        #pragma unroll
        for (int s = 0; s < 4; ++s) {
            int cc = c0 + s*32;
            if (w < 4) {                           // B rows x = w*16..+16
                int row = w*16 + (lane>>2);
                const short* gB = xb + ((size_t)(h + 1 + dy)*66 + (row + dx + 1))*512
                                  + cc + (lane&3)*8;
                gl2lds16(gB, &Bsh[s][(w*16)*32]);
            } else if (w < 6) {                    // A rows oc = (w-4)*16..+16
                int row = (w-4)*16 + (lane>>2);
                const short* gA = Woffb + (size_t)row*4608 + tap*512 + cc + (lane&3)*8;
                gl2lds16(gA, &Ash[s][((w-4)*16)*32]);
            }
        }
        __syncthreads();
        #pragma unroll
        for (int s = 0; s < 4; ++s) {
            short8 af  = *(const short8*)&Ash[s][(wr*16 + ln)*32 + q*8];
            short8 bfr = *(const short8*)&Bsh[s][(wc*16 + ln)*32 + q*8];
            acc = __builtin_amdgcn_mfma_f32_16x16x32_bf16(af, bfr, acc, 0, 0, 0);
        }
        __syncthreads();
    }
    int x = wc*16 + ln;
    #pragma unroll
    for (int r = 0; r < 4; ++r) {
        int oc = wr*16 + q*4 + r;
        if (oc < 27)
            offv[((b*27 + oc)*64 + h)*64 + x] = acc[r] + off_b[oc];
    }
}

// ---------------- sample: masked bilinear im2col -> G[pos][tap*256+c] bf16 ----
// grid 2048 x 256 (b x h x 4 p-groups); uint2 (4-channel) vectorized gathers
__global__ void k_sample(const short* __restrict__ Xpad,
                         const float* __restrict__ offv,
                         uint2* __restrict__ G)        // G as uint2 (4 bf16)
{
    __shared__ int   c_off[144*4];
    __shared__ float c_w[144*4];
    int bb = blockIdx.x;
    int pg = bb & 3, h = (bb >> 2) & 63, b = bb >> 8;
    int p0 = pg * 16;
    int t = threadIdx.x;

    if (t < 144) {
        int p = p0 + t / 9, k = t % 9;
        int base = (b*27)*4096 + h*64 + p;
        float dy = offv[base + k*4096];
        float dx = offv[base + (9+k)*4096];
        float ms = offv[base + (18+k)*4096];
        ms = 1.f / (1.f + expf(-ms));
        float py = (float)h + (float)(k/3 - 1) + dy;
        float px = (float)p + (float)(k%3 - 1) + dx;
        float y0f = floorf(py), x0f = floorf(px);
        float wy = py - y0f, wx = px - x0f;
        int y0 = (int)y0f, x0 = (int)x0f;
        int y1 = y0 + 1, x1 = x0 + 1;
        float vy0 = (y0 >= 0 && y0 < 64) ? 1.f : 0.f;
        float vy1 = (y1 >= 0 && y1 < 64) ? 1.f : 0.f;
        float vx0 = (x0 >= 0 && x0 < 64) ? 1.f : 0.f;
        float vx1 = (x1 >= 0 && x1 < 64) ? 1.f : 0.f;
        int y0c = min(max(y0,0),63), y1c = min(max(y1,0),63);
        int x0c = min(max(x0,0),63), x1c = min(max(x1,0),63);
        // offsets in uint2 units (4-ch groups): cell*512/4 = cell*128
        c_off[t*4+0] = ((y0c+1)*66 + x0c+1)*128;
        c_off[t*4+1] = ((y0c+1)*66 + x1c+1)*128;
        c_off[t*4+2] = ((y1c+1)*66 + x0c+1)*128;
        c_off[t*4+3] = ((y1c+1)*66 + x1c+1)*128;
        c_w[t*4+0] = ms * (1.f-wy)*(1.f-wx) * vy0*vx0;
        c_w[t*4+1] = ms * (1.f-wy)*wx       * vy0*vx1;
        c_w[t*4+2] = ms * wy*(1.f-wx)       * vy1*vx0;
        c_w[t*4+3] = ms * wy*wx             * vy1*vx1;
    }
    __syncthreads();

    int tc = t & 63, tg = t >> 6;                  // tc: uint2 lane (64 = 256 ch/tap)
    const uint2* fT = (const uint2*)Xpad + (size_t)b*(XPB/4);
    size_t rb = ((size_t)b*4096 + h*64 + p0);
    #pragma unroll
    for (int pi = 0; pi < 4; ++pi) {
        int pl = tg*4 + pi;                        // wave-uniform local p
        size_t grow = (rb + pl)*576;               // G row in uint2 units (2304/4)
        #pragma unroll
        for (int k = 0; k < 9; ++k) {
            int e = pl*9 + k;
            const int4   co = *(const int4*)&c_off[e*4];
            const float4 cw = *(const float4*)&c_w[e*4];
            uint2 u0 = fT[co.x + tc];
            uint2 u1 = fT[co.y + tc];
            uint2 u2 = fT[co.z + tc];
            uint2 u3 = fT[co.w + tc];
            float g0 = cw.x*blo(u0.x) + cw.y*blo(u1.x) + cw.z*blo(u2.x) + cw.w*blo(u3.x);
            float g1 = cw.x*bhi(u0.x) + cw.y*bhi(u1.x) + cw.z*bhi(u2.x) + cw.w*bhi(u3.x);
            float g2 = cw.x*blo(u0.y) + cw.y*blo(u1.y) + cw.z*blo(u2.y) + cw.w*blo(u3.y);
            float g3 = cw.x*bhi(u0.y) + cw.y*bhi(u1.y) + cw.z*bhi(u2.y) + cw.w*bhi(u3.y);
            G[grow + k*64 + tc] = make_uint2(pack2(g0, g1), pack2(g2, g3));
        }
    }
}

// ---------------- dcn GEMM via bf16 MFMA: M=256(o) N=64(pos) K=2304 ----------
// grid 512 x 512 thr (8 waves, m-strip 32); BK=64 as 2 stride-32 sub-chunks
// per barrier window (36 iters, 16 MFMA/wave/window)
__global__ __launch_bounds__(512, 4) void k_gemm(
    const short* __restrict__ G,      // [32768][2304] bf16
    const short* __restrict__ Wbf,    // [256][2304] bf16
    const short* __restrict__ Xpad,   // residual: proj half
    const float* __restrict__ inv2f, const float* __restrict__ bias2f,
    float* __restrict__ out)
{
    __shared__ short Ash[2][256*32];   // 32 KB [o][32k] x2
    __shared__ short Bsh[2][64*32];    //  8 KB [pos][32k] x2
    int bid = blockIdx.x;
    int n0 = bid * 64;
    int b = n0 >> 12, hw0 = n0 & 4095;
    int t = threadIdx.x;
    int lane = t & 63, w = t >> 6;
    int ln = lane & 15, q = lane >> 4;

    f32x4 acc[2][4] = {};
    for (int kc2 = 0; kc2 < 36; ++kc2) {
        #pragma unroll
        for (int s = 0; s < 2; ++s) {
            int kcol = (kc2*2 + s)*32 + (lane&3)*8;
            #pragma unroll
            for (int i = 0; i < 2; ++i) {
                int row = w*32 + i*16 + (lane>>2);
                gl2lds16(Wbf + (size_t)row*2304 + kcol, &Ash[s][(w*32 + i*16)*32]);
            }
            if (w < 4) {
                int row = w*16 + (lane>>2);
                gl2lds16(G + (size_t)(n0 + row)*2304 + kcol, &Bsh[s][(w*16)*32]);
            }
        }
        __syncthreads();
        #pragma unroll
        for (int s = 0; s < 2; ++s) {
            short8 af[2], bfr[4];
            #pragma unroll
            for (int i = 0; i < 2; ++i)
                af[i] = *(const short8*)&Ash[s][(w*32 + i*16 + ln)*32 + q*8];
            #pragma unroll
            for (int j = 0; j < 4; ++j)
                bfr[j] = *(const short8*)&Bsh[s][(j*16 + ln)*32 + q*8];
            #pragma unroll
            for (int i = 0; i < 2; ++i)
                #pragma unroll
                for (int j = 0; j < 4; ++j)
                    acc[i][j] = __builtin_amdgcn_mfma_f32_16x16x32_bf16(af[i], bfr[j], acc[i][j], 0, 0, 0);
        }
        __syncthreads();
    }

    // epilogue: bn2 + residual(from Xpad proj half) + relu
    int h = hw0 >> 6;
    #pragma unroll
    for (int i = 0; i < 2; ++i) {
        int ob = w*32 + i*16 + q*4;
        #pragma unroll
        for (int j = 0; j < 4; ++j) {
            int p = j*16 + ln;
            size_t xb = ((size_t)(b*66 + h + 1)*66 + p + 1)*512 + 256 + ob;
            short4v pr = *(const short4v*)&Xpad[xb];
            #pragma unroll
            for (int r = 0; r < 4; ++r) {
                int o = ob + r;
                size_t idx = ((size_t)(b*256 + o))*4096 + hw0 + p;
                float rs = bs2f(((const short*)&pr)[r]);
                float v = rs + acc[i][j][r]*inv2f[o] + bias2f[o];
                out[idx] = v < 0.f ? 0.f : v;   // NaN-propagating relu
            }
        }
    }
}

extern "C" void kernel_launch(void* const* d_in, const int* in_sizes, int n_in,
                              void* d_out, int out_size, void* d_ws, size_t ws_size,
                              hipStream_t stream)
{
    const float* feature = (const float*)d_in[0];
    const float* p1_w  = (const float*)d_in[1];
    const float* p1_b  = (const float*)d_in[2];
    const float* bn1_g = (const float*)d_in[3];
    const float* bn1_b = (const float*)d_in[4];
    const float* bn1_m = (const float*)d_in[5];
    const float* bn1_v = (const float*)d_in[6];
    const float* off_w = (const float*)d_in[7];
    const float* off_b = (const float*)d_in[8];
    const float* dcn_w = (const float*)d_in[9];
    const float* dcn_b = (const float*)d_in[10];
    const float* bn2_g = (const float*)d_in[11];
    const float* bn2_b = (const float*)d_in[12];
    const float* bn2_m = (const float*)d_in[13];
    const float* bn2_v = (const float*)d_in[14];

    // Workspace (float-slot offsets). Total 47,956,736 f = 191.8 MB (proven).
    float* ws = (float*)d_ws;
    short* Xpad   = (short*)ws;                 // 17,842,176 sh = 8,921,088 f
    float* offbuf = ws + 8921088;               //    884,736 f
    short* p1_wb  = (short*)(ws + 9805824);     //     65,536 sh = 32,768 f
    short* Woffb  = (short*)(ws + 9838592);     //    147,456 sh = 73,728 f
    short* Wbf    = (short*)(ws + 9912320);     //    589,824 sh = 294,912 f
    float* bias1f = ws + 10207232;              //        256
    float* inv2f  = ws + 10207488;              //        256
    float* bias2f = ws + 10207744;              //        256
    short* G      = (short*)(ws + 10208000);    // 75,497,472 sh = 37,748,736 f

    k_prep<<<9249, 256, 0, stream>>>(p1_w, p1_b, bn1_g, bn1_b, bn1_m, bn1_v,
                                     off_w, dcn_w, dcn_b, bn2_g, bn2_b, bn2_m, bn2_v,
                                     p1_wb, Woffb, Wbf, bias1f, inv2f, bias2f,
                                     (unsigned*)Xpad);
    k_featT<<<2048, 256, 0, stream>>>(feature, Xpad);
    k_projm<<<512, 512, 0, stream>>>(Xpad, p1_wb, bias1f);
    k_offm<<<512, 512, 0, stream>>>(Xpad, Woffb, off_b, offbuf);
    k_sample<<<2048, 256, 0, stream>>>(Xpad, offbuf, (uint2*)G);
    k_gemm<<<512, 512, 0, stream>>>(G, Wbf, Xpad, inv2f, bias2f, (float*)d_out);
}

// Round 10
// 268.119 us; speedup vs baseline: 1.3422x; 1.0188x over previous
//
#include <hip/hip_runtime.h>
#include <hip/hip_bf16.h>
#include <math.h>

typedef __attribute__((ext_vector_type(8))) short short8;
typedef __attribute__((ext_vector_type(4))) short short4v;
typedef __attribute__((ext_vector_type(4))) float f32x4;

__device__ __forceinline__ float bs2f(short s){
    union { unsigned u; float f; } x; x.u = ((unsigned)(unsigned short)s) << 16; return x.f;
}
__device__ __forceinline__ short f2bs(float f){
    union { float f; unsigned u; } x; x.f = f;
    unsigned r = x.u + 0x7fff + ((x.u >> 16) & 1);   // round-nearest-even
    return (short)(r >> 16);
}
__device__ __forceinline__ float blo(unsigned u){
    union { unsigned u; float f; } x; x.u = u << 16; return x.f;
}
__device__ __forceinline__ float bhi(unsigned u){
    union { unsigned u; float f; } x; x.u = u & 0xffff0000u; return x.f;
}
__device__ __forceinline__ unsigned pack2(float lo, float hi){
    union { float f; unsigned u; } a, b; a.f = lo; b.f = hi;
    unsigned rl = a.u + 0x7fff + ((a.u >> 16) & 1);
    unsigned rh = b.u + 0x7fff + ((b.u >> 16) & 1);
    return (rl >> 16) | (rh & 0xffff0000u);
}
__device__ __forceinline__ void gl2lds16(const void* g, void* l){
    __builtin_amdgcn_global_load_lds(
        (const __attribute__((address_space(1))) void*)g,
        (__attribute__((address_space(3))) void*)l, 16, 0, 0);
}

// Xpad[b][y][x][c]: y,x in [0,66), c in [0,512). Interior (y=h+1,x=w+1).
// c<256: flipped feature (= feature[b][c][h][63-w]); c>=256: proj.
#define XPB ((size_t)66*66*512)

// LDS k-quad XOR swizzle: LDS quad p of row r holds global quad p^((r>>1)&3).
// Staging lane L (row L>>2, quad L&3) sources global quad (L&3)^((L>>3)&3);
// fragment read for (row ln, quad q) uses LDS quad q^((ln>>1)&3).
// Turns the 8-way fragment-read bank conflict (64B row stride) into 2-way (free).

// ---------------- prep: BN folding + weight transposes + Xpad halo zero ------
// grid 9249 x 256
__global__ void k_prep(const float* __restrict__ p1_w, const float* __restrict__ p1_b,
                       const float* __restrict__ bn1_g, const float* __restrict__ bn1_b,
                       const float* __restrict__ bn1_m, const float* __restrict__ bn1_v,
                       const float* __restrict__ off_w,
                       const float* __restrict__ dcn_w, const float* __restrict__ dcn_b,
                       const float* __restrict__ bn2_g, const float* __restrict__ bn2_b,
                       const float* __restrict__ bn2_m, const float* __restrict__ bn2_v,
                       short* __restrict__ p1_wb, short* __restrict__ Woffb,
                       short* __restrict__ Wbf,
                       float* __restrict__ bias1f, float* __restrict__ inv2f,
                       float* __restrict__ bias2f, unsigned* __restrict__ XpadU)
{
    int blk = blockIdx.x, t = threadIdx.x;
    if (blk == 0) {
        float inv1 = bn1_g[t] / sqrtf(bn1_v[t] + 1e-5f);
        bias1f[t] = p1_b[t] * inv1 + bn1_b[t] - bn1_m[t] * inv1;
        float inv2 = bn2_g[t] / sqrtf(bn2_v[t] + 1e-5f);
        inv2f[t] = inv2;
        bias2f[t] = dcn_b[t] * inv2 + bn2_b[t] - bn2_m[t] * inv2;
    } else if (blk <= 256) {
        int ci = blk - 1;
        float inv1 = bn1_g[t] / sqrtf(bn1_v[t] + 1e-5f);
        p1_wb[t*256 + ci] = f2bs(p1_w[t*256 + ci] * inv1);   // [o][ci], bn1 folded
    } else if (blk <= 2560) {
        int ck = blk - 257;                             // ck = c*9+tap (original order)
        int c = ck / 9, tap = ck % 9;
        Wbf[t*2304 + tap*256 + c] = f2bs(dcn_w[t*2304 + ck]);  // [o][tap*256+c]
    } else if (blk <= 7168) {
        int e = blk - 2561;                             // e = tap*512+ci (new K order)
        if (t < 32) {
            int tap = e >> 9, ci = e & 511;
            float v = off_w[((t < 27) ? t : 0)*4608 + ci*9 + tap];
            Woffb[t*4608 + e] = (t < 27) ? f2bs(v) : (short)0;  // [oc pad32][tap*512+ci]
        }
    } else {
        int hb = blk - 7169;                            // halo zero, 260 cells/b
        int b = hb / 260, i = hb % 260;
        int y, x;
        if (i < 66)       { y = 0;  x = i; }
        else if (i < 132) { y = 65; x = i - 66; }
        else { int j = i - 132; y = 1 + (j >> 1); x = (j & 1) * 65; }
        XpadU[((size_t)(b*66 + y)*66 + x)*256 + t] = 0u;
    }
}

// ---------------- transpose+flip -> Xpad flip half (bf16, channels-last) -----
// grid 2048 x 256  (8 b * 64 h * 4 c-groups)
__global__ void k_featT(const float* __restrict__ feature, short* __restrict__ Xpad)
{
    __shared__ float tile[64][65];
    int bb = blockIdx.x;
    int cg = bb & 3, h = (bb >> 2) & 63, b = bb >> 8;
    int c0 = cg * 64;
    int t = threadIdx.x;
    int lw = t & 63, li = t >> 6;
    #pragma unroll
    for (int j = 0; j < 16; ++j) {
        int cl = j*4 + li;
        tile[cl][63 - lw] = feature[((b*256 + c0 + cl)*64 + h)*64 + lw];
    }
    __syncthreads();
    #pragma unroll
    for (int j = 0; j < 16; ++j) {
        int wl = j*4 + li;
        Xpad[((size_t)(b*66 + h+1)*66 + (wl+1))*512 + c0 + lw] = f2bs(tile[lw][wl]);
    }
}

// ---------------- proj via MFMA: M=256(o) N=64(pos=one (b,h) row) K=256 -------
// grid 512 x 512 thr (8 waves, m-strip 32/wave); writes Xpad proj half
__global__ __launch_bounds__(512, 4) void k_projm(
    short* Xpad, const short* __restrict__ p1_wb, const float* __restrict__ bias1f)
{
    __shared__ short Ash[256*32];   // 16 KB [o][32k]
    __shared__ short Bsh[64*32];    //  4 KB [x][32k]
    int bid = blockIdx.x;
    int b = bid >> 6, h = bid & 63;
    int t = threadIdx.x;
    int lane = t & 63, w = t >> 6;
    int ln = lane & 15, q = lane >> 4;
    int r16 = lane >> 2;
    int sq  = (lane & 3) ^ ((lane >> 3) & 3);       // staging swizzled quad
    int rq  = (q ^ ((ln >> 1) & 3)) * 8;            // read swizzled quad offset
    size_t rowbase = (size_t)(b*66 + h + 1)*66;

    f32x4 acc[2][4] = {};
    for (int kt = 0; kt < 8; ++kt) {
        int kcol = kt*32 + sq*8;
        #pragma unroll
        for (int i = 0; i < 2; ++i) {
            int row = w*32 + i*16 + r16;
            gl2lds16(p1_wb + (size_t)row*256 + kcol, Ash + (w*32 + i*16)*32);
        }
        if (w < 4) {
            int x = w*16 + r16;                       // output w-coord
            gl2lds16(Xpad + (rowbase + (64 - x))*512 + kcol, Bsh + (w*16)*32);
        }
        __syncthreads();
        short8 af[2], bfr[4];
        #pragma unroll
        for (int i = 0; i < 2; ++i)
            af[i] = *(const short8*)&Ash[(w*32 + i*16 + ln)*32 + rq];
        #pragma unroll
        for (int j = 0; j < 4; ++j)
            bfr[j] = *(const short8*)&Bsh[(j*16 + ln)*32 + rq];
        #pragma unroll
        for (int i = 0; i < 2; ++i)
            #pragma unroll
            for (int j = 0; j < 4; ++j)
                acc[i][j] = __builtin_amdgcn_mfma_f32_16x16x32_bf16(af[i], bfr[j], acc[i][j], 0, 0, 0);
        __syncthreads();
    }
    #pragma unroll
    for (int i = 0; i < 2; ++i) {
        int ob = w*32 + i*16 + q*4;
        #pragma unroll
        for (int j = 0; j < 4; ++j) {
            int x = j*16 + ln;
            size_t xb = (rowbase + x + 1)*512 + 256 + ob;
            short4v st;
            st.x = f2bs(acc[i][j][0] + bias1f[ob]);
            st.y = f2bs(acc[i][j][1] + bias1f[ob+1]);
            st.z = f2bs(acc[i][j][2] + bias1f[ob+2]);
            st.w = f2bs(acc[i][j][3] + bias1f[ob+3]);
            *(short4v*)&Xpad[xb] = st;
        }
    }
}

// ---------------- offset conv via MFMA: M=32(27 oc) N=64(x) K=4608 ------------
// grid 512 ((b,h) rows) x 512 thr (8 waves: 2m x 4n); BK=128 as 4 stride-32
// sub-chunks per barrier window (36 iters, 4 MFMA/wave/window)
__global__ __launch_bounds__(512, 4) void k_offm(
    const short* __restrict__ Xpad, const short* __restrict__ Woffb,
    const float* __restrict__ off_b, float* __restrict__ offv)
{
    __shared__ short Ash[4][32*32];   //  8 KB [oc][32k] x4
    __shared__ short Bsh[4][64*32];   // 16 KB [x][32k] x4
    int bid = blockIdx.x;
    int b = bid >> 6, h = bid & 63;
    int t = threadIdx.x;
    int lane = t & 63, w = t >> 6;
    int ln = lane & 15, q = lane >> 4;
    int wr = w >> 2, wc = w & 3;
    int r16 = lane >> 2;
    int sq  = (lane & 3) ^ ((lane >> 3) & 3);
    int rq  = (q ^ ((ln >> 1) & 3)) * 8;
    const short* xb = Xpad + (size_t)b*XPB;

    f32x4 acc = {};
    for (int it = 0; it < 36; ++it) {
        int tap = it >> 2, c0 = (it & 3) << 7;    // 128-ch chunk within tap
        int dy = tap/3 - 1, dx = tap%3 - 1;
        #pragma unroll
        for (int s = 0; s < 4; ++s) {
            int cc = c0 + s*32 + sq*8;
            if (w < 4) {                           // B rows x = w*16..+16
                int row = w*16 + r16;
                const short* gB = xb + ((size_t)(h + 1 + dy)*66 + (row + dx + 1))*512 + cc;
                gl2lds16(gB, &Bsh[s][(w*16)*32]);
            } else if (w < 6) {                    // A rows oc = (w-4)*16..+16
                int row = (w-4)*16 + r16;
                const short* gA = Woffb + (size_t)row*4608 + tap*512 + cc;
                gl2lds16(gA, &Ash[s][((w-4)*16)*32]);
            }
        }
        __syncthreads();
        #pragma unroll
        for (int s = 0; s < 4; ++s) {
            short8 af  = *(const short8*)&Ash[s][(wr*16 + ln)*32 + rq];
            short8 bfr = *(const short8*)&Bsh[s][(wc*16 + ln)*32 + rq];
            acc = __builtin_amdgcn_mfma_f32_16x16x32_bf16(af, bfr, acc, 0, 0, 0);
        }
        __syncthreads();
    }
    int x = wc*16 + ln;
    #pragma unroll
    for (int r = 0; r < 4; ++r) {
        int oc = wr*16 + q*4 + r;
        if (oc < 27)
            offv[((b*27 + oc)*64 + h)*64 + x] = acc[r] + off_b[oc];
    }
}

// ---------------- sample: masked bilinear im2col -> G[pos][tap*256+c] bf16 ----
// grid 2048 x 256 (b x h x 4 p-groups); uint2 (4-channel) vectorized gathers
__global__ void k_sample(const short* __restrict__ Xpad,
                         const float* __restrict__ offv,
                         uint2* __restrict__ G)        // G as uint2 (4 bf16)
{
    __shared__ int   c_off[144*4];
    __shared__ float c_w[144*4];
    int bb = blockIdx.x;
    int pg = bb & 3, h = (bb >> 2) & 63, b = bb >> 8;
    int p0 = pg * 16;
    int t = threadIdx.x;

    if (t < 144) {
        int p = p0 + t / 9, k = t % 9;
        int base = (b*27)*4096 + h*64 + p;
        float dy = offv[base + k*4096];
        float dx = offv[base + (9+k)*4096];
        float ms = offv[base + (18+k)*4096];
        ms = 1.f / (1.f + expf(-ms));
        float py = (float)h + (float)(k/3 - 1) + dy;
        float px = (float)p + (float)(k%3 - 1) + dx;
        float y0f = floorf(py), x0f = floorf(px);
        float wy = py - y0f, wx = px - x0f;
        int y0 = (int)y0f, x0 = (int)x0f;
        int y1 = y0 + 1, x1 = x0 + 1;
        float vy0 = (y0 >= 0 && y0 < 64) ? 1.f : 0.f;
        float vy1 = (y1 >= 0 && y1 < 64) ? 1.f : 0.f;
        float vx0 = (x0 >= 0 && x0 < 64) ? 1.f : 0.f;
        float vx1 = (x1 >= 0 && x1 < 64) ? 1.f : 0.f;
        int y0c = min(max(y0,0),63), y1c = min(max(y1,0),63);
        int x0c = min(max(x0,0),63), x1c = min(max(x1,0),63);
        // offsets in uint2 units (4-ch groups): cell*512/4 = cell*128
        c_off[t*4+0] = ((y0c+1)*66 + x0c+1)*128;
        c_off[t*4+1] = ((y0c+1)*66 + x1c+1)*128;
        c_off[t*4+2] = ((y1c+1)*66 + x0c+1)*128;
        c_off[t*4+3] = ((y1c+1)*66 + x1c+1)*128;
        c_w[t*4+0] = ms * (1.f-wy)*(1.f-wx) * vy0*vx0;
        c_w[t*4+1] = ms * (1.f-wy)*wx       * vy0*vx1;
        c_w[t*4+2] = ms * wy*(1.f-wx)       * vy1*vx0;
        c_w[t*4+3] = ms * wy*wx             * vy1*vx1;
    }
    __syncthreads();

    int tc = t & 63, tg = t >> 6;                  // tc: uint2 lane (64 = 256 ch/tap)
    const uint2* fT = (const uint2*)Xpad + (size_t)b*(XPB/4);
    size_t rb = ((size_t)b*4096 + h*64 + p0);
    #pragma unroll
    for (int pi = 0; pi < 4; ++pi) {
        int pl = tg*4 + pi;                        // wave-uniform local p
        size_t grow = (rb + pl)*576;               // G row in uint2 units (2304/4)
        #pragma unroll
        for (int k = 0; k < 9; ++k) {
            int e = pl*9 + k;
            const int4   co = *(const int4*)&c_off[e*4];
            const float4 cw = *(const float4*)&c_w[e*4];
            uint2 u0 = fT[co.x + tc];
            uint2 u1 = fT[co.y + tc];
            uint2 u2 = fT[co.z + tc];
            uint2 u3 = fT[co.w + tc];
            float g0 = cw.x*blo(u0.x) + cw.y*blo(u1.x) + cw.z*blo(u2.x) + cw.w*blo(u3.x);
            float g1 = cw.x*bhi(u0.x) + cw.y*bhi(u1.x) + cw.z*bhi(u2.x) + cw.w*bhi(u3.x);
            float g2 = cw.x*blo(u0.y) + cw.y*blo(u1.y) + cw.z*blo(u2.y) + cw.w*blo(u3.y);
            float g3 = cw.x*bhi(u0.y) + cw.y*bhi(u1.y) + cw.z*bhi(u2.y) + cw.w*bhi(u3.y);
            G[grow + k*64 + tc] = make_uint2(pack2(g0, g1), pack2(g2, g3));
        }
    }
}

// ---------------- dcn GEMM via bf16 MFMA: M=256(o) N=64(pos) K=2304 ----------
// grid 512 x 512 thr (8 waves, m-strip 32); BK=64 as 2 stride-32 sub-chunks
// per barrier window (36 iters, 16 MFMA/wave/window)
__global__ __launch_bounds__(512, 4) void k_gemm(
    const short* __restrict__ G,      // [32768][2304] bf16
    const short* __restrict__ Wbf,    // [256][2304] bf16
    const short* __restrict__ Xpad,   // residual: proj half
    const float* __restrict__ inv2f, const float* __restrict__ bias2f,
    float* __restrict__ out)
{
    __shared__ short Ash[2][256*32];   // 32 KB [o][32k] x2
    __shared__ short Bsh[2][64*32];    //  8 KB [pos][32k] x2
    int bid = blockIdx.x;
    int n0 = bid * 64;
    int b = n0 >> 12, hw0 = n0 & 4095;
    int t = threadIdx.x;
    int lane = t & 63, w = t >> 6;
    int ln = lane & 15, q = lane >> 4;
    int r16 = lane >> 2;
    int sq  = (lane & 3) ^ ((lane >> 3) & 3);
    int rq  = (q ^ ((ln >> 1) & 3)) * 8;

    f32x4 acc[2][4] = {};
    for (int kc2 = 0; kc2 < 36; ++kc2) {
        #pragma unroll
        for (int s = 0; s < 2; ++s) {
            int kcol = (kc2*2 + s)*32 + sq*8;
            #pragma unroll
            for (int i = 0; i < 2; ++i) {
                int row = w*32 + i*16 + r16;
                gl2lds16(Wbf + (size_t)row*2304 + kcol, &Ash[s][(w*32 + i*16)*32]);
            }
            if (w < 4) {
                int row = w*16 + r16;
                gl2lds16(G + (size_t)(n0 + row)*2304 + kcol, &Bsh[s][(w*16)*32]);
            }
        }
        __syncthreads();
        #pragma unroll
        for (int s = 0; s < 2; ++s) {
            short8 af[2], bfr[4];
            #pragma unroll
            for (int i = 0; i < 2; ++i)
                af[i] = *(const short8*)&Ash[s][(w*32 + i*16 + ln)*32 + rq];
            #pragma unroll
            for (int j = 0; j < 4; ++j)
                bfr[j] = *(const short8*)&Bsh[s][(j*16 + ln)*32 + rq];
            #pragma unroll
            for (int i = 0; i < 2; ++i)
                #pragma unroll
                for (int j = 0; j < 4; ++j)
                    acc[i][j] = __builtin_amdgcn_mfma_f32_16x16x32_bf16(af[i], bfr[j], acc[i][j], 0, 0, 0);
        }
        __syncthreads();
    }

    // epilogue: bn2 + residual(from Xpad proj half) + relu
    int h = hw0 >> 6;
    #pragma unroll
    for (int i = 0; i < 2; ++i) {
        int ob = w*32 + i*16 + q*4;
        #pragma unroll
        for (int j = 0; j < 4; ++j) {
            int p = j*16 + ln;
            size_t xb = ((size_t)(b*66 + h + 1)*66 + p + 1)*512 + 256 + ob;
            short4v pr = *(const short4v*)&Xpad[xb];
            #pragma unroll
            for (int r = 0; r < 4; ++r) {
                int o = ob + r;
                size_t idx = ((size_t)(b*256 + o))*4096 + hw0 + p;
                float rs = bs2f(((const short*)&pr)[r]);
                float v = rs + acc[i][j][r]*inv2f[o] + bias2f[o];
                out[idx] = v < 0.f ? 0.f : v;   // NaN-propagating relu
            }
        }
    }
}

extern "C" void kernel_launch(void* const* d_in, const int* in_sizes, int n_in,
                              void* d_out, int out_size, void* d_ws, size_t ws_size,
                              hipStream_t stream)
{
    const float* feature = (const float*)d_in[0];
    const float* p1_w  = (const float*)d_in[1];
    const float* p1_b  = (const float*)d_in[2];
    const float* bn1_g = (const float*)d_in[3];
    const float* bn1_b = (const float*)d_in[4];
    const float* bn1_m = (const float*)d_in[5];
    const float* bn1_v = (const float*)d_in[6];
    const float* off_w = (const float*)d_in[7];
    const float* off_b = (const float*)d_in[8];
    const float* dcn_w = (const float*)d_in[9];
    const float* dcn_b = (const float*)d_in[10];
    const float* bn2_g = (const float*)d_in[11];
    const float* bn2_b = (const float*)d_in[12];
    const float* bn2_m = (const float*)d_in[13];
    const float* bn2_v = (const float*)d_in[14];

    // Workspace (float-slot offsets). Total 47,956,736 f = 191.8 MB (proven).
    float* ws = (float*)d_ws;
    short* Xpad   = (short*)ws;                 // 17,842,176 sh = 8,921,088 f
    float* offbuf = ws + 8921088;               //    884,736 f
    short* p1_wb  = (short*)(ws + 9805824);     //     65,536 sh = 32,768 f
    short* Woffb  = (short*)(ws + 9838592);     //    147,456 sh = 73,728 f
    short* Wbf    = (short*)(ws + 9912320);     //    589,824 sh = 294,912 f
    float* bias1f = ws + 10207232;              //        256
    float* inv2f  = ws + 10207488;              //        256
    float* bias2f = ws + 10207744;              //        256
    short* G      = (short*)(ws + 10208000);    // 75,497,472 sh = 37,748,736 f

    k_prep<<<9249, 256, 0, stream>>>(p1_w, p1_b, bn1_g, bn1_b, bn1_m, bn1_v,
                                     off_w, dcn_w, dcn_b, bn2_g, bn2_b, bn2_m, bn2_v,
                                     p1_wb, Woffb, Wbf, bias1f, inv2f, bias2f,
                                     (unsigned*)Xpad);
    k_featT<<<2048, 256, 0, stream>>>(feature, Xpad);
    k_projm<<<512, 512, 0, stream>>>(Xpad, p1_wb, bias1f);
    k_offm<<<512, 512, 0, stream>>>(Xpad, Woffb, off_b, offbuf);
    k_sample<<<2048, 256, 0, stream>>>(Xpad, offbuf, (uint2*)G);
    k_gemm<<<512, 512, 0, stream>>>(G, Wbf, Xpad, inv2f, bias2f, (float*)d_out);
}